// Round 5
// baseline (947.006 us; speedup 1.0000x reference)
//
#include <hip/hip_runtime.h>

// ---------------------------------------------------------------------------
// ConvLSTMNet round 5:
//  - lstm: cell0+cell1 of the same (sub,tile) merged into one 512-thread block
//    sharing the x LDS tile (51 KB). 220 blocks -> 1 block/CU everywhere,
//    2 waves/SIMD (was: 184 CUs x 2 serialized blocks = 3050 cyc/step).
//  - fc: 8-deep pipelined W loads (8 independent float4 in flight per wave)
//    to cover ~900cyc HBM latency; bigger k-split grids. acc[16][4], no spill.
// ---------------------------------------------------------------------------

#define T_STEPS 256
#define PIX 55
#define MT 16          // sequences per tile (MFMA M-tile)
#define TILES 110      // 1760 / 16
#define LOG2E 1.4426950408889634f
#define FC_KCMAX 128
#define FC_PIPE 8

typedef float f32x4 __attribute__((ext_vector_type(4)));
typedef __bf16 bf16x8 __attribute__((ext_vector_type(8)));

__global__ __launch_bounds__(512) void lstm_kernel(
    const float* __restrict__ x1, const float* __restrict__ x2,
    const float* __restrict__ wx1, const float* __restrict__ wh1,
    const float* __restrict__ bx1, const float* __restrict__ bh1,
    const float* __restrict__ wx2, const float* __restrict__ wh2,
    const float* __restrict__ bx2, const float* __restrict__ bh2,
    float* __restrict__ feat)   // [64][7040]: row sub*32+b, col (cell*64+u)*55+p
{
    int bid  = blockIdx.x;            // 0..219
    int sub  = bid / TILES;
    int tile = bid % TILES;
    const float* x = sub ? x2 : x1;

    int tid  = threadIdx.x;           // 0..511
    int cell = tid >> 8;              // waves 0-3: cell0 ; waves 4-7: cell1
    int t8   = tid & 255;
    int w    = t8 >> 6;               // wave-in-cell = unit subtile (16 units)
    int l    = t8 & 63;
    int quad = l >> 4;
    int c16  = l & 15;

    const float* wx = cell ? wx2 : wx1;
    const float* wh = cell ? wh2 : wh1;
    const float* bx = cell ? bx2 : bx1;
    const float* bh = cell ? bh2 : bh1;

    __shared__ float xl[MT * 514];                          // shared by both cells, 32.9 KB
    __shared__ __align__(16) __bf16 hb[2][2][2][MT][72];    // [cell][buf][hi/lo][m][u] 18.4 KB

    // ---- stage x for this (sub,tile): 16 seq x 256 steps x 2 ch ----
    {
        int seq0 = tile * MT;
        for (int i = 0; i < 16; ++i) {
            int idx = tid + 512 * i;          // m*512 + t*2 + c
            int m = idx >> 9;
            int tc = idx & 511;
            int t = tc >> 1, c = tc & 1;
            int seq = seq0 + m;
            int b = seq / PIX, p = seq % PIX;
            xl[m * 514 + tc] = x[((b * T_STEPS + t) * 2 + c) * PIX + p];
        }
    }
    // ---- zero h buffers ----
    {
        __bf16* hz = &hb[0][0][0][0][0];
        for (int i = tid; i < 2 * 2 * 2 * MT * 72; i += 512) hz[i] = (__bf16)0.0f;
    }

    // ---- register-resident wh B-fragments for 4 gates (hi+lo) ----
    bf16x8 Bhi[4][2], Blo[4][2];
    float btot[4], wx0v[4], wx1v[4];
#pragma unroll
    for (int g = 0; g < 4; ++g) {
        int n = 64 * g + 16 * w + c16;
        btot[g] = bx[n] + bh[n];
        wx0v[g] = wx[n];
        wx1v[g] = wx[256 + n];
#pragma unroll
        for (int q = 0; q < 2; ++q) {
#pragma unroll
            for (int j = 0; j < 8; ++j) {
                int k = 32 * q + 8 * quad + j;
                float wv = wh[k * 256 + n];
                __bf16 hi = (__bf16)wv;
                Bhi[g][q][j] = hi;
                Blo[g][q][j] = (__bf16)(wv - (float)hi);
            }
        }
    }

    float cst[4]  = {0.f, 0.f, 0.f, 0.f};
    float hfin[4] = {0.f, 0.f, 0.f, 0.f};

    __syncthreads();

    for (int t = 0; t < T_STEPS; ++t) {
        int rb = t & 1, wb = rb ^ 1;
        int tx = cell ? (T_STEPS - 1 - t) : t;   // cell1 runs time-reversed

        bf16x8 Ah[2], Al[2];
#pragma unroll
        for (int q = 0; q < 2; ++q) {
            Ah[q] = *(const bf16x8*)&hb[cell][rb][0][c16][32 * q + 8 * quad];
            Al[q] = *(const bf16x8*)&hb[cell][rb][1][c16][32 * q + 8 * quad];
        }
        float xa[4], xb_[4];
#pragma unroll
        for (int r = 0; r < 4; ++r) {
            float2 v = *(const float2*)&xl[(4 * quad + r) * 514 + tx * 2];
            xa[r] = v.x; xb_[r] = v.y;
        }

        f32x4 acc[4];
#pragma unroll
        for (int g = 0; g < 4; ++g) {
#pragma unroll
            for (int r = 0; r < 4; ++r)
                acc[g][r] = fmaf(xb_[r], wx1v[g], fmaf(xa[r], wx0v[g], btot[g]));
        }
#pragma unroll
        for (int g = 0; g < 4; ++g) {
            acc[g] = __builtin_amdgcn_mfma_f32_16x16x32_bf16(Ah[0], Bhi[g][0], acc[g], 0, 0, 0);
            acc[g] = __builtin_amdgcn_mfma_f32_16x16x32_bf16(Ah[1], Bhi[g][1], acc[g], 0, 0, 0);
            acc[g] = __builtin_amdgcn_mfma_f32_16x16x32_bf16(Al[0], Bhi[g][0], acc[g], 0, 0, 0);
            acc[g] = __builtin_amdgcn_mfma_f32_16x16x32_bf16(Al[1], Bhi[g][1], acc[g], 0, 0, 0);
            acc[g] = __builtin_amdgcn_mfma_f32_16x16x32_bf16(Ah[0], Blo[g][0], acc[g], 0, 0, 0);
            acc[g] = __builtin_amdgcn_mfma_f32_16x16x32_bf16(Ah[1], Blo[g][1], acc[g], 0, 0, 0);
        }

#pragma unroll
        for (int r = 0; r < 4; ++r) {
            float iv = acc[0][r], fv = acc[1][r], ov = acc[2][r], gv = acc[3][r];
            float ei = __builtin_amdgcn_exp2f(-LOG2E * iv);
            float ef = __builtin_amdgcn_exp2f(-LOG2E * fv);
            float eo = __builtin_amdgcn_exp2f(-LOG2E * ov);
            float eg = __builtin_amdgcn_exp2f(-2.0f * LOG2E * gv);
            float sf  = __builtin_amdgcn_rcpf(1.0f + ef);
            float itg = (1.0f - eg) * __builtin_amdgcn_rcpf((1.0f + ei) * (1.0f + eg));
            float c   = fmaf(sf, cst[r], itg);
            cst[r] = c;
            float ec = __builtin_amdgcn_exp2f(-2.0f * LOG2E * c);
            float h  = (1.0f - ec) * __builtin_amdgcn_rcpf((1.0f + eo) * (1.0f + ec));
            hfin[r] = h;
            int m = 4 * quad + r, u = 16 * w + c16;
            __bf16 hi = (__bf16)h;
            hb[cell][wb][0][m][u] = hi;
            hb[cell][wb][1][m][u] = (__bf16)(h - (float)hi);
        }
        __syncthreads();
    }

#pragma unroll
    for (int r = 0; r < 4; ++r) {
        int m = 4 * quad + r;
        int seq = tile * MT + m;
        int b = seq / PIX, p = seq % PIX;
        int u = 16 * w + c16;
        feat[(size_t)(sub * 32 + b) * 7040 + (cell * 64 + u) * PIX + p] = hfin[r];
    }
}

// ---------------------------------------------------------------------------
// FC: out[64][N] += A[64][K] @ W[K][N] (+bias on y==0).
// Block: 64 m (wave w -> rows 16w..16w+15) x 256 n (lane owns 4 n).
// 8-deep pipelined W float4 loads (independent, all in flight) to cover HBM
// latency. A chunk in LDS, read as same-address broadcast b128. Split-K
// over blockIdx.y with fp32 atomics. Partial n-blocks take a guarded path.
// ---------------------------------------------------------------------------
__global__ __launch_bounds__(256, 2) void fc_gemm(const float* __restrict__ A,
                                                  const float* __restrict__ W,
                                                  const float* __restrict__ bias,
                                                  float* __restrict__ out,
                                                  int K, int N, int kchunk) {
    int k0  = blockIdx.y * kchunk;
    int kcur = min(kchunk, K - k0);
    if (kcur <= 0) return;                              // uniform, pre-barrier

    __shared__ __align__(16) float al[FC_KCMAX * 68];   // [kc][m pad68]
    int tid = threadIdx.x;
    int l   = tid & 63;
    int wv  = tid >> 6;

    // ---- stage A[0:64][k0:k0+kcur] -> al[kc][m] (coalesced global reads) ----
    for (int mg = 0; mg < 64; mg += 4) {
        int m = mg + wv;
        const float* ar = A + (size_t)m * K + k0;
        for (int kc = l; kc < kcur; kc += 64)
            al[kc * 68 + m] = ar[kc];
    }
    __syncthreads();

    int n0 = blockIdx.x * 256 + 4 * l;
    bool blockfull = ((int)(blockIdx.x + 1) * 256 <= N);
    float acc[16][4];
#pragma unroll
    for (int m = 0; m < 16; ++m)
#pragma unroll
        for (int c = 0; c < 4; ++c) acc[m][c] = 0.0f;

    if (blockIdx.y == 0) {
        float bv[4];
#pragma unroll
        for (int c = 0; c < 4; ++c) bv[c] = (n0 + c < N) ? bias[n0 + c] : 0.0f;
#pragma unroll
        for (int m = 0; m < 16; ++m)
#pragma unroll
            for (int c = 0; c < 4; ++c) acc[m][c] = bv[c];
    }

    const float* wr = W + (size_t)k0 * N;
    if (blockfull) {
        int kc0 = 0;
        for (; kc0 + FC_PIPE <= kcur; kc0 += FC_PIPE) {
            float4 wbuf[FC_PIPE];
#pragma unroll
            for (int j = 0; j < FC_PIPE; ++j)
                wbuf[j] = *(const float4*)&wr[(size_t)(kc0 + j) * N + n0];   // 8 in flight
#pragma unroll
            for (int j = 0; j < FC_PIPE; ++j) {
                float wv4[4] = {wbuf[j].x, wbuf[j].y, wbuf[j].z, wbuf[j].w};
                const float4* ap = (const float4*)&al[(kc0 + j) * 68 + 16 * wv];
#pragma unroll
                for (int i = 0; i < 4; ++i) {
                    float4 a = ap[i];
                    float as[4] = {a.x, a.y, a.z, a.w};
#pragma unroll
                    for (int r = 0; r < 4; ++r)
#pragma unroll
                        for (int c = 0; c < 4; ++c)
                            acc[4 * i + r][c] = fmaf(as[r], wv4[c], acc[4 * i + r][c]);
                }
            }
        }
        for (; kc0 < kcur; ++kc0) {
            float4 t = *(const float4*)&wr[(size_t)kc0 * N + n0];
            float wv4[4] = {t.x, t.y, t.z, t.w};
            const float4* ap = (const float4*)&al[kc0 * 68 + 16 * wv];
#pragma unroll
            for (int i = 0; i < 4; ++i) {
                float4 a = ap[i];
                float as[4] = {a.x, a.y, a.z, a.w};
#pragma unroll
                for (int r = 0; r < 4; ++r)
#pragma unroll
                    for (int c = 0; c < 4; ++c)
                        acc[4 * i + r][c] = fmaf(as[r], wv4[c], acc[4 * i + r][c]);
            }
        }
    } else {
        for (int kc = 0; kc < kcur; ++kc) {
            size_t kb = (size_t)kc * N;
            float wv4[4];
#pragma unroll
            for (int c = 0; c < 4; ++c) { int n = n0 + c; wv4[c] = (n < N) ? wr[kb + n] : 0.0f; }
            const float4* ap = (const float4*)&al[kc * 68 + 16 * wv];
#pragma unroll
            for (int i = 0; i < 4; ++i) {
                float4 a = ap[i];
                float as[4] = {a.x, a.y, a.z, a.w};
#pragma unroll
                for (int r = 0; r < 4; ++r)
#pragma unroll
                    for (int c = 0; c < 4; ++c)
                        acc[4 * i + r][c] = fmaf(as[r], wv4[c], acc[4 * i + r][c]);
            }
        }
    }

#pragma unroll
    for (int i = 0; i < 16; ++i) {
        int m = 16 * wv + i;
        float* orow = out + (size_t)m * N;
#pragma unroll
        for (int c = 0; c < 4; ++c) {
            int n = n0 + c;
            if (n < N) atomicAdd(&orow[n], acc[i][c]);
        }
    }
}

__global__ __launch_bounds__(256) void zero2(float* __restrict__ a, int na,
                                             float* __restrict__ b, int nb) {
    int i = blockIdx.x * 256 + threadIdx.x;
    if (i < na) a[i] = 0.0f;
    if (i < nb) b[i] = 0.0f;
}

extern "C" void kernel_launch(void* const* d_in, const int* in_sizes, int n_in,
                              void* d_out, int out_size, void* d_ws, size_t ws_size,
                              hipStream_t stream) {
    const float* x1  = (const float*)d_in[0];
    const float* x2  = (const float*)d_in[1];
    const float* wx1 = (const float*)d_in[2];
    const float* wh1 = (const float*)d_in[3];
    const float* bx1 = (const float*)d_in[4];
    const float* bh1 = (const float*)d_in[5];
    const float* wx2 = (const float*)d_in[6];
    const float* wh2 = (const float*)d_in[7];
    const float* bx2 = (const float*)d_in[8];
    const float* bh2 = (const float*)d_in[9];
    const float* fw2 = (const float*)d_in[10];
    const float* fb2 = (const float*)d_in[11];
    const float* fw3 = (const float*)d_in[12];
    const float* fb3 = (const float*)d_in[13];
    const float* fw4 = (const float*)d_in[14];
    const float* fb4 = (const float*)d_in[15];
    const float* fw5 = (const float*)d_in[16];
    const float* fb5 = (const float*)d_in[17];

    char* ws = (char*)d_ws;
    float* feat = (float*)ws;                                   // [64][7040]
    float* t1   = feat + (size_t)64 * 7040;                     // [64][3400]
    float* t2   = t1   + (size_t)64 * 3400;                     // [64][1000]
    float* t3   = t2   + (size_t)64 * 1000;                     // [64][500]
    float* o    = (float*)d_out;                                // [64][50]

    lstm_kernel<<<dim3(220), dim3(512), 0, stream>>>(
        x1, x2, wx1, wh1, bx1, bh1, wx2, wh2, bx2, bh2, feat);

    // zero t1,t2,t3 (contiguous 64*4900 floats) and d_out
    zero2<<<dim3(1225), dim3(256), 0, stream>>>(t1, 64 * 4900, o, 64 * 50);

    fc_gemm<<<dim3(14, 56), dim3(256), 0, stream>>>(feat, fw2, fb2, t1, 7040, 3400, 126);
    fc_gemm<<<dim3( 4, 64), dim3(256), 0, stream>>>(t1,   fw3, fb3, t2, 3400, 1000,  54);
    fc_gemm<<<dim3( 2, 25), dim3(256), 0, stream>>>(t2,   fw4, fb4, t3, 1000,  500,  40);
    fc_gemm<<<dim3( 1, 25), dim3(256), 0, stream>>>(t3,   fw5, fb5, o,   500,   50,  20);
}

// Round 6
// 775.047 us; speedup vs baseline: 1.2219x; 1.2219x over previous
//
#include <hip/hip_runtime.h>

// ---------------------------------------------------------------------------
// ConvLSTMNet round 6:
//  - lstm: MFMA operands swapped. W (register-resident) is now the A-operand,
//    h (LDS) the B-operand -> D rows = units, cols = seqs. Each thread's 4 h
//    outputs are u-consecutive: packed bf16x4 b64 writes (was 8 scattered
//    b16), x read is one b64 (was 4). LDS insts/wave-step: 16 -> 7.
//    (R5 analysis: lstm was LDS-pipe bound at ~128 LDS insts/CU/step.)
//  - FC: atomics eliminated (R5: ~17M dword atomicAdds ~= the missing 600us).
//    fc_gemm writes split-K partials with plain stores; fc_reduce sums
//    partials + bias. n-tile 128, acc[16][2]=32 regs, 8-deep W pipeline.
// ---------------------------------------------------------------------------

#define T_STEPS 256
#define PIX 55
#define MT 16          // sequences per tile (MFMA N-dim now)
#define TILES 110      // 1760 / 16
#define LOG2E 1.4426950408889634f
#define FC_SUB 126
#define FC_PIPE 8

typedef float f32x4 __attribute__((ext_vector_type(4)));
typedef __bf16 bf16x8 __attribute__((ext_vector_type(8)));
typedef __bf16 bf16x4 __attribute__((ext_vector_type(4)));

__global__ __launch_bounds__(256) void lstm_kernel(
    const float* __restrict__ x1, const float* __restrict__ x2,
    const float* __restrict__ wx1, const float* __restrict__ wh1,
    const float* __restrict__ bx1, const float* __restrict__ bh1,
    const float* __restrict__ wx2, const float* __restrict__ wh2,
    const float* __restrict__ bx2, const float* __restrict__ bh2,
    float* __restrict__ feat)   // [64][7040]: row sub*32+b, col (cell*64+u)*55+p
{
    int bid  = blockIdx.x;            // 0..439
    int tile = bid % TILES;
    int cc   = bid / TILES;           // 0..3
    int sub  = cc >> 1, cell = cc & 1;
    const float* x  = sub  ? x2  : x1;
    const float* wx = cell ? wx2 : wx1;
    const float* wh = cell ? wh2 : wh1;
    const float* bx = cell ? bx2 : bx1;
    const float* bh = cell ? bh2 : bh1;

    int tid  = threadIdx.x;
    int w    = tid >> 6;              // wave id = unit subtile (units 16w..16w+15)
    int l    = tid & 63;
    int quad = l >> 4;
    int c16  = l & 15;

    __shared__ float xl[MT * 514];                        // [seq][t*2+c], pad 514
    __shared__ __align__(16) __bf16 hb[2][2][MT][72];     // [buf][hi/lo][seq][u pad72]

    // ---- stage x for this block's 16 sequences (all 256 steps) ----
    {
        int seq0 = tile * MT;
        for (int i = 0; i < 32; ++i) {
            int idx = tid + 256 * i;          // m*512 + t*2 + c
            int m = idx >> 9;
            int tc = idx & 511;
            int t = tc >> 1, c = tc & 1;
            int seq = seq0 + m;
            int b = seq / PIX, p = seq % PIX;
            xl[m * 514 + tc] = x[((b * T_STEPS + t) * 2 + c) * PIX + p];
        }
    }
    // ---- zero h buffers ----
    {
        __bf16* hz = &hb[0][0][0][0];
        for (int i = tid; i < 2 * 2 * MT * 72; i += 256) hz[i] = (__bf16)0.0f;
    }

    // ---- W as A-operand fragments (hi+lo), per gate & K-slab ----
    // A[m'][k]: lane m' = c16 (unit 16w+c16), k = 32q + 8*quad + j
    bf16x8 Whi[4][2], Wlo[4][2];
    float btot[4][4], wxa[4][4], wxb[4][4];
#pragma unroll
    for (int g = 0; g < 4; ++g) {
        int col = 64 * g + 16 * w + c16;
#pragma unroll
        for (int r = 0; r < 4; ++r) {
            int u = 64 * g + 16 * w + 4 * quad + r;   // this thread's C-row units
            btot[g][r] = bx[u] + bh[u];
            wxa[g][r]  = wx[u];
            wxb[g][r]  = wx[256 + u];
        }
#pragma unroll
        for (int q = 0; q < 2; ++q) {
#pragma unroll
            for (int j = 0; j < 8; ++j) {
                int k = 32 * q + 8 * quad + j;
                float wv = wh[k * 256 + col];
                __bf16 hi = (__bf16)wv;
                Whi[g][q][j] = hi;
                Wlo[g][q][j] = (__bf16)(wv - (float)hi);
            }
        }
    }

    float cst[4]  = {0.f, 0.f, 0.f, 0.f};
    float hfin[4] = {0.f, 0.f, 0.f, 0.f};

    __syncthreads();

    for (int t = 0; t < T_STEPS; ++t) {
        int rb = t & 1, wb = rb ^ 1;
        int tx = cell ? (T_STEPS - 1 - t) : t;   // cell1 runs time-reversed

        // B-operand: h. B[k][n]: lane n = c16 (seq), k = 32q + 8quad + j
        // -> contiguous in hb row c16. Same for hi and lo.
        bf16x8 Bh[2], Bl[2];
#pragma unroll
        for (int q = 0; q < 2; ++q) {
            Bh[q] = *(const bf16x8*)&hb[rb][0][c16][32 * q + 8 * quad];
            Bl[q] = *(const bf16x8*)&hb[rb][1][c16][32 * q + 8 * quad];
        }
        // x for this thread's seq (= c16): one b64 read
        float2 xv = *(const float2*)&xl[c16 * 514 + tx * 2];

        f32x4 acc[4];
#pragma unroll
        for (int g = 0; g < 4; ++g) {
#pragma unroll
            for (int r = 0; r < 4; ++r)
                acc[g][r] = fmaf(xv.y, wxb[g][r], fmaf(xv.x, wxa[g][r], btot[g][r]));
        }
#pragma unroll
        for (int g = 0; g < 4; ++g) {
            acc[g] = __builtin_amdgcn_mfma_f32_16x16x32_bf16(Whi[g][0], Bh[0], acc[g], 0, 0, 0);
            acc[g] = __builtin_amdgcn_mfma_f32_16x16x32_bf16(Whi[g][1], Bh[1], acc[g], 0, 0, 0);
            acc[g] = __builtin_amdgcn_mfma_f32_16x16x32_bf16(Wlo[g][0], Bh[0], acc[g], 0, 0, 0);
            acc[g] = __builtin_amdgcn_mfma_f32_16x16x32_bf16(Wlo[g][1], Bh[1], acc[g], 0, 0, 0);
            acc[g] = __builtin_amdgcn_mfma_f32_16x16x32_bf16(Whi[g][0], Bl[0], acc[g], 0, 0, 0);
            acc[g] = __builtin_amdgcn_mfma_f32_16x16x32_bf16(Whi[g][1], Bl[1], acc[g], 0, 0, 0);
        }

        // ---- state update: C rows = units u = 16w + 4quad + r, col = seq c16 ----
        bf16x4 ph, pl;
#pragma unroll
        for (int r = 0; r < 4; ++r) {
            float iv = acc[0][r], fv = acc[1][r], ov = acc[2][r], gv = acc[3][r];
            float ei = __builtin_amdgcn_exp2f(-LOG2E * iv);
            float ef = __builtin_amdgcn_exp2f(-LOG2E * fv);
            float eo = __builtin_amdgcn_exp2f(-LOG2E * ov);
            float eg = __builtin_amdgcn_exp2f(-2.0f * LOG2E * gv);
            float sf  = __builtin_amdgcn_rcpf(1.0f + ef);
            float itg = (1.0f - eg) * __builtin_amdgcn_rcpf((1.0f + ei) * (1.0f + eg));
            float c   = fmaf(sf, cst[r], itg);
            cst[r] = c;
            float ec = __builtin_amdgcn_exp2f(-2.0f * LOG2E * c);
            float h  = (1.0f - ec) * __builtin_amdgcn_rcpf((1.0f + eo) * (1.0f + ec));
            hfin[r] = h;
            __bf16 hi = (__bf16)h;
            ph[r] = hi;
            pl[r] = (__bf16)(h - (float)hi);
        }
        // packed b64 writes: row = seq c16, u-start = 16w + 4quad (r-consecutive)
        *(bf16x4*)&hb[wb][0][c16][16 * w + 4 * quad] = ph;
        *(bf16x4*)&hb[wb][1][c16][16 * w + 4 * quad] = pl;
        __syncthreads();
    }

    // ---- final feature write: this thread owns seq=c16, units 16w+4quad+r ----
    {
        int seq = tile * MT + c16;
        int b = seq / PIX, p = seq % PIX;
#pragma unroll
        for (int r = 0; r < 4; ++r) {
            int u = 16 * w + 4 * quad + r;
            feat[(size_t)(sub * 32 + b) * 7040 + (cell * 64 + u) * PIX + p] = hfin[r];
        }
    }
}

// ---------------------------------------------------------------------------
// FC: part[split][64][N] = A[64][K-chunk] @ W[K-chunk][N]. Plain stores, no
// atomics. Block: 64 m (wave w -> rows 16w..16w+15) x 128 n (lane owns 2 n).
// A sub-chunks staged in LDS (broadcast b128 reads); 8-deep pipelined W
// float2 loads. fc_reduce sums partials + bias into the final activation.
// ---------------------------------------------------------------------------
__global__ __launch_bounds__(256) void fc_gemm(const float* __restrict__ A,
                                               const float* __restrict__ W,
                                               float* __restrict__ part,
                                               int K, int N, int kchunk) {
    __shared__ __align__(16) float al[FC_SUB * 68];   // [kc][m pad68]
    int tid = threadIdx.x;
    int l   = tid & 63;
    int wv  = tid >> 6;
    int k0   = blockIdx.y * kchunk;
    int kend = min(K, k0 + kchunk);

    int n0 = blockIdx.x * 128 + 2 * l;
    bool nfull = ((int)(blockIdx.x + 1) * 128 <= N);
    float acc[16][2];
#pragma unroll
    for (int i = 0; i < 16; ++i) { acc[i][0] = 0.0f; acc[i][1] = 0.0f; }

    for (int ks = k0; ks < kend; ks += FC_SUB) {
        int kcur = min(FC_SUB, kend - ks);
        __syncthreads();                       // protect al reuse
        // stage A[0:64][ks:ks+kcur] -> al[kc][m] (coalesced reads, lane=kc)
        for (int mg = 0; mg < 64; mg += 4) {
            int m = mg + wv;
            const float* ar = A + (size_t)m * K + ks;
            for (int kc = l; kc < kcur; kc += 64)
                al[kc * 68 + m] = ar[kc];
        }
        __syncthreads();

        const float* wr = W + (size_t)ks * N;
        if (nfull) {
            int kc0 = 0;
            for (; kc0 + FC_PIPE <= kcur; kc0 += FC_PIPE) {
                float2 wbuf[FC_PIPE];
#pragma unroll
                for (int j = 0; j < FC_PIPE; ++j)
                    wbuf[j] = *(const float2*)&wr[(size_t)(kc0 + j) * N + n0];
#pragma unroll
                for (int j = 0; j < FC_PIPE; ++j) {
                    float w0 = wbuf[j].x, w1 = wbuf[j].y;
                    const float4* ap = (const float4*)&al[(kc0 + j) * 68 + 16 * wv];
#pragma unroll
                    for (int i = 0; i < 4; ++i) {
                        float4 a = ap[i];
                        float as[4] = {a.x, a.y, a.z, a.w};
#pragma unroll
                        for (int r = 0; r < 4; ++r) {
                            acc[4 * i + r][0] = fmaf(as[r], w0, acc[4 * i + r][0]);
                            acc[4 * i + r][1] = fmaf(as[r], w1, acc[4 * i + r][1]);
                        }
                    }
                }
            }
            for (; kc0 < kcur; ++kc0) {
                float2 t = *(const float2*)&wr[(size_t)kc0 * N + n0];
                const float4* ap = (const float4*)&al[kc0 * 68 + 16 * wv];
#pragma unroll
                for (int i = 0; i < 4; ++i) {
                    float4 a = ap[i];
                    float as[4] = {a.x, a.y, a.z, a.w};
#pragma unroll
                    for (int r = 0; r < 4; ++r) {
                        acc[4 * i + r][0] = fmaf(as[r], t.x, acc[4 * i + r][0]);
                        acc[4 * i + r][1] = fmaf(as[r], t.y, acc[4 * i + r][1]);
                    }
                }
            }
        } else {
            for (int kc = 0; kc < kcur; ++kc) {
                size_t kb = (size_t)kc * N;
                float w0 = (n0     < N) ? wr[kb + n0]     : 0.0f;
                float w1 = (n0 + 1 < N) ? wr[kb + n0 + 1] : 0.0f;
                const float4* ap = (const float4*)&al[kc * 68 + 16 * wv];
#pragma unroll
                for (int i = 0; i < 4; ++i) {
                    float4 a = ap[i];
                    float as[4] = {a.x, a.y, a.z, a.w};
#pragma unroll
                    for (int r = 0; r < 4; ++r) {
                        acc[4 * i + r][0] = fmaf(as[r], w0, acc[4 * i + r][0]);
                        acc[4 * i + r][1] = fmaf(as[r], w1, acc[4 * i + r][1]);
                    }
                }
            }
        }
    }

    float* pr = part + (size_t)blockIdx.y * 64 * N;
#pragma unroll
    for (int i = 0; i < 16; ++i) {
        int m = 16 * wv + i;
        if (n0 < N)     pr[(size_t)m * N + n0]     = acc[i][0];
        if (n0 + 1 < N) pr[(size_t)m * N + n0 + 1] = acc[i][1];
    }
}

__global__ __launch_bounds__(256) void fc_reduce(const float* __restrict__ part,
                                                 const float* __restrict__ bias,
                                                 float* __restrict__ out,
                                                 int S, int N) {
    int n = blockIdx.x * 256 + threadIdx.x;
    int m = blockIdx.y;
    if (n >= N) return;
    float s = bias[n];
    for (int i = 0; i < S; ++i)
        s += part[(size_t)i * 64 * N + (size_t)m * N + n];
    out[(size_t)m * N + n] = s;
}

extern "C" void kernel_launch(void* const* d_in, const int* in_sizes, int n_in,
                              void* d_out, int out_size, void* d_ws, size_t ws_size,
                              hipStream_t stream) {
    const float* x1  = (const float*)d_in[0];
    const float* x2  = (const float*)d_in[1];
    const float* wx1 = (const float*)d_in[2];
    const float* wh1 = (const float*)d_in[3];
    const float* bx1 = (const float*)d_in[4];
    const float* bh1 = (const float*)d_in[5];
    const float* wx2 = (const float*)d_in[6];
    const float* wh2 = (const float*)d_in[7];
    const float* bx2 = (const float*)d_in[8];
    const float* bh2 = (const float*)d_in[9];
    const float* fw2 = (const float*)d_in[10];
    const float* fb2 = (const float*)d_in[11];
    const float* fw3 = (const float*)d_in[12];
    const float* fb3 = (const float*)d_in[13];
    const float* fw4 = (const float*)d_in[14];
    const float* fb4 = (const float*)d_in[15];
    const float* fw5 = (const float*)d_in[16];
    const float* fb5 = (const float*)d_in[17];

    char* ws = (char*)d_ws;
    float* feat = (float*)ws;                                   // [64][7040]
    float* t1   = feat + (size_t)64 * 7040;                     // [64][3400]
    float* t2   = t1   + (size_t)64 * 3400;                     // [64][1000]
    float* t3   = t2   + (size_t)64 * 1000;                     // [64][500]
    float* part = t3   + (size_t)64 * 500;                      // up to 14*64*3400
    float* o    = (float*)d_out;                                // [64][50]

    lstm_kernel<<<dim3(440), dim3(256), 0, stream>>>(
        x1, x2, wx1, wh1, bx1, bh1, wx2, wh2, bx2, bh2, feat);

    fc_gemm<<<dim3(27, 14), dim3(256), 0, stream>>>(feat, fw2, part, 7040, 3400, 504);
    fc_reduce<<<dim3(14, 64), dim3(256), 0, stream>>>(part, fb2, t1, 14, 3400);

    fc_gemm<<<dim3(8, 25), dim3(256), 0, stream>>>(t1, fw3, part, 3400, 1000, 136);
    fc_reduce<<<dim3(4, 64), dim3(256), 0, stream>>>(part, fb3, t2, 25, 1000);

    fc_gemm<<<dim3(4, 50), dim3(256), 0, stream>>>(t2, fw4, part, 1000, 500, 20);
    fc_reduce<<<dim3(2, 64), dim3(256), 0, stream>>>(part, fb4, t3, 50, 500);

    fc_gemm<<<dim3(1, 25), dim3(256), 0, stream>>>(t3, fw5, part, 500, 50, 20);
    fc_reduce<<<dim3(1, 64), dim3(256), 0, stream>>>(part, fb5, o, 25, 50);
}

// Round 7
// 590.309 us; speedup vs baseline: 1.6043x; 1.3130x over previous
//
#include <hip/hip_runtime.h>

// ---------------------------------------------------------------------------
// ConvLSTMNet round 7:
//  - lstm: unchanged from R6 (W as MFMA A-operand, packed b64 h writes).
//  - FC "slim": anti-spill design. Lane owns ONE n column: acc[16] = 16
//    VGPRs (~50 total, no spill possible). W: 16-deep scalar pipeline,
//    256B/wave coalesced. A: staged per 128-kc chunk with 32 independent
//    unrolled coalesced loads. Grids 2-6x bigger (fc2: 756 blocks ~ 3/CU).
//    Split-K partials + fc_reduce (no atomics).
// ---------------------------------------------------------------------------

#define T_STEPS 256
#define PIX 55
#define MT 16          // sequences per tile (MFMA N-dim)
#define TILES 110      // 1760 / 16
#define LOG2E 1.4426950408889634f
#define FC_SUB 128     // kc per LDS stage
#define FC_GRP 16      // W pipeline depth

typedef float f32x4 __attribute__((ext_vector_type(4)));
typedef __bf16 bf16x8 __attribute__((ext_vector_type(8)));
typedef __bf16 bf16x4 __attribute__((ext_vector_type(4)));

__global__ __launch_bounds__(256) void lstm_kernel(
    const float* __restrict__ x1, const float* __restrict__ x2,
    const float* __restrict__ wx1, const float* __restrict__ wh1,
    const float* __restrict__ bx1, const float* __restrict__ bh1,
    const float* __restrict__ wx2, const float* __restrict__ wh2,
    const float* __restrict__ bx2, const float* __restrict__ bh2,
    float* __restrict__ feat)   // [64][7040]: row sub*32+b, col (cell*64+u)*55+p
{
    int bid  = blockIdx.x;            // 0..439
    int tile = bid % TILES;
    int cc   = bid / TILES;           // 0..3
    int sub  = cc >> 1, cell = cc & 1;
    const float* x  = sub  ? x2  : x1;
    const float* wx = cell ? wx2 : wx1;
    const float* wh = cell ? wh2 : wh1;
    const float* bx = cell ? bx2 : bx1;
    const float* bh = cell ? bh2 : bh1;

    int tid  = threadIdx.x;
    int w    = tid >> 6;              // wave id = unit subtile (units 16w..16w+15)
    int l    = tid & 63;
    int quad = l >> 4;
    int c16  = l & 15;

    __shared__ float xl[MT * 514];                        // [seq][t*2+c], pad 514
    __shared__ __align__(16) __bf16 hb[2][2][MT][72];     // [buf][hi/lo][seq][u pad72]

    // ---- stage x for this block's 16 sequences (all 256 steps) ----
    {
        int seq0 = tile * MT;
        for (int i = 0; i < 32; ++i) {
            int idx = tid + 256 * i;          // m*512 + t*2 + c
            int m = idx >> 9;
            int tc = idx & 511;
            int t = tc >> 1, c = tc & 1;
            int seq = seq0 + m;
            int b = seq / PIX, p = seq % PIX;
            xl[m * 514 + tc] = x[((b * T_STEPS + t) * 2 + c) * PIX + p];
        }
    }
    // ---- zero h buffers ----
    {
        __bf16* hz = &hb[0][0][0][0];
        for (int i = tid; i < 2 * 2 * MT * 72; i += 256) hz[i] = (__bf16)0.0f;
    }

    // ---- W as A-operand fragments (hi+lo), per gate & K-slab ----
    bf16x8 Whi[4][2], Wlo[4][2];
    float btot[4][4], wxa[4][4], wxb[4][4];
#pragma unroll
    for (int g = 0; g < 4; ++g) {
        int col = 64 * g + 16 * w + c16;
#pragma unroll
        for (int r = 0; r < 4; ++r) {
            int u = 64 * g + 16 * w + 4 * quad + r;   // this thread's C-row units
            btot[g][r] = bx[u] + bh[u];
            wxa[g][r]  = wx[u];
            wxb[g][r]  = wx[256 + u];
        }
#pragma unroll
        for (int q = 0; q < 2; ++q) {
#pragma unroll
            for (int j = 0; j < 8; ++j) {
                int k = 32 * q + 8 * quad + j;
                float wv = wh[k * 256 + col];
                __bf16 hi = (__bf16)wv;
                Whi[g][q][j] = hi;
                Wlo[g][q][j] = (__bf16)(wv - (float)hi);
            }
        }
    }

    float cst[4]  = {0.f, 0.f, 0.f, 0.f};
    float hfin[4] = {0.f, 0.f, 0.f, 0.f};

    __syncthreads();

    for (int t = 0; t < T_STEPS; ++t) {
        int rb = t & 1, wb = rb ^ 1;
        int tx = cell ? (T_STEPS - 1 - t) : t;   // cell1 runs time-reversed

        bf16x8 Bh[2], Bl[2];
#pragma unroll
        for (int q = 0; q < 2; ++q) {
            Bh[q] = *(const bf16x8*)&hb[rb][0][c16][32 * q + 8 * quad];
            Bl[q] = *(const bf16x8*)&hb[rb][1][c16][32 * q + 8 * quad];
        }
        float2 xv = *(const float2*)&xl[c16 * 514 + tx * 2];

        f32x4 acc[4];
#pragma unroll
        for (int g = 0; g < 4; ++g) {
#pragma unroll
            for (int r = 0; r < 4; ++r)
                acc[g][r] = fmaf(xv.y, wxb[g][r], fmaf(xv.x, wxa[g][r], btot[g][r]));
        }
#pragma unroll
        for (int g = 0; g < 4; ++g) {
            acc[g] = __builtin_amdgcn_mfma_f32_16x16x32_bf16(Whi[g][0], Bh[0], acc[g], 0, 0, 0);
            acc[g] = __builtin_amdgcn_mfma_f32_16x16x32_bf16(Whi[g][1], Bh[1], acc[g], 0, 0, 0);
            acc[g] = __builtin_amdgcn_mfma_f32_16x16x32_bf16(Wlo[g][0], Bh[0], acc[g], 0, 0, 0);
            acc[g] = __builtin_amdgcn_mfma_f32_16x16x32_bf16(Wlo[g][1], Bh[1], acc[g], 0, 0, 0);
            acc[g] = __builtin_amdgcn_mfma_f32_16x16x32_bf16(Whi[g][0], Bl[0], acc[g], 0, 0, 0);
            acc[g] = __builtin_amdgcn_mfma_f32_16x16x32_bf16(Whi[g][1], Bl[1], acc[g], 0, 0, 0);
        }

        bf16x4 ph, pl;
#pragma unroll
        for (int r = 0; r < 4; ++r) {
            float iv = acc[0][r], fv = acc[1][r], ov = acc[2][r], gv = acc[3][r];
            float ei = __builtin_amdgcn_exp2f(-LOG2E * iv);
            float ef = __builtin_amdgcn_exp2f(-LOG2E * fv);
            float eo = __builtin_amdgcn_exp2f(-LOG2E * ov);
            float eg = __builtin_amdgcn_exp2f(-2.0f * LOG2E * gv);
            float sf  = __builtin_amdgcn_rcpf(1.0f + ef);
            float itg = (1.0f - eg) * __builtin_amdgcn_rcpf((1.0f + ei) * (1.0f + eg));
            float c   = fmaf(sf, cst[r], itg);
            cst[r] = c;
            float ec = __builtin_amdgcn_exp2f(-2.0f * LOG2E * c);
            float h  = (1.0f - ec) * __builtin_amdgcn_rcpf((1.0f + eo) * (1.0f + ec));
            hfin[r] = h;
            __bf16 hi = (__bf16)h;
            ph[r] = hi;
            pl[r] = (__bf16)(h - (float)hi);
        }
        *(bf16x4*)&hb[wb][0][c16][16 * w + 4 * quad] = ph;
        *(bf16x4*)&hb[wb][1][c16][16 * w + 4 * quad] = pl;
        __syncthreads();
    }

    {
        int seq = tile * MT + c16;
        int b = seq / PIX, p = seq % PIX;
#pragma unroll
        for (int r = 0; r < 4; ++r) {
            int u = 16 * w + 4 * quad + r;
            feat[(size_t)(sub * 32 + b) * 7040 + (cell * 64 + u) * PIX + p] = hfin[r];
        }
    }
}

// ---------------------------------------------------------------------------
// FC slim: part[split][64][N] = A[64][kchunk] @ W[kchunk][N].
// Block = 64 m x 64 n. Lane owns ONE n (acc[16] per wave-m-group = 16 VGPR).
// Wave w -> rows 16w..16w+15 (broadcast b128 A reads). W: 16-deep scalar
// pipeline, coalesced 256 B/wave. A: 32 independent unrolled coalesced loads
// per 128-kc stage. No atomics; fc_reduce sums partials + bias.
// ---------------------------------------------------------------------------
__global__ __launch_bounds__(256) void fc_gemm(const float* __restrict__ A,
                                               const float* __restrict__ W,
                                               float* __restrict__ part,
                                               int K, int N, int kchunk) {
    __shared__ __align__(16) float al[FC_SUB * 68];   // [kc][m pad68]
    int tid = threadIdx.x;
    int l   = tid & 63;
    int wv  = tid >> 6;
    int k0   = blockIdx.y * kchunk;
    int kend = min(K, k0 + kchunk);

    int n  = blockIdx.x * 64 + l;
    int ne = min(n, N - 1);                // clamped load index (stores guarded)

    float acc[16];
#pragma unroll
    for (int i = 0; i < 16; ++i) acc[i] = 0.0f;

    for (int ks = k0; ks < kend; ks += FC_SUB) {
        int kcur = min(FC_SUB, kend - ks);
        __syncthreads();                   // protect al reuse
        // ---- stage A[0:64][ks:ks+kcur]: 32 independent coalesced loads ----
        if (kcur == FC_SUB) {
#pragma unroll
            for (int i = 0; i < 32; ++i) {
                int idx = tid + 256 * i;       // m = idx>>7, kc = idx&127
                int m = idx >> 7, kc = idx & 127;
                al[kc * 68 + m] = A[(size_t)m * K + ks + kc];
            }
        } else {
#pragma unroll
            for (int i = 0; i < 32; ++i) {
                int idx = tid + 256 * i;
                int m = idx >> 7, kc = idx & 127;
                if (kc < kcur) al[kc * 68 + m] = A[(size_t)m * K + ks + kc];
            }
        }
        __syncthreads();

        const float* wr = W + (size_t)ks * N + ne;
        int kc0 = 0;
        for (; kc0 + FC_GRP <= kcur; kc0 += FC_GRP) {
            float wbuf[FC_GRP];
#pragma unroll
            for (int j = 0; j < FC_GRP; ++j)
                wbuf[j] = wr[(size_t)(kc0 + j) * N];    // 16 independent, coalesced
#pragma unroll
            for (int j = 0; j < FC_GRP; ++j) {
                const float4* ap = (const float4*)&al[(kc0 + j) * 68 + 16 * wv];
#pragma unroll
                for (int i = 0; i < 4; ++i) {
                    float4 a = ap[i];
                    acc[4 * i + 0] = fmaf(a.x, wbuf[j], acc[4 * i + 0]);
                    acc[4 * i + 1] = fmaf(a.y, wbuf[j], acc[4 * i + 1]);
                    acc[4 * i + 2] = fmaf(a.z, wbuf[j], acc[4 * i + 2]);
                    acc[4 * i + 3] = fmaf(a.w, wbuf[j], acc[4 * i + 3]);
                }
            }
        }
        for (; kc0 < kcur; ++kc0) {
            float wvv = wr[(size_t)kc0 * N];
            const float4* ap = (const float4*)&al[kc0 * 68 + 16 * wv];
#pragma unroll
            for (int i = 0; i < 4; ++i) {
                float4 a = ap[i];
                acc[4 * i + 0] = fmaf(a.x, wvv, acc[4 * i + 0]);
                acc[4 * i + 1] = fmaf(a.y, wvv, acc[4 * i + 1]);
                acc[4 * i + 2] = fmaf(a.z, wvv, acc[4 * i + 2]);
                acc[4 * i + 3] = fmaf(a.w, wvv, acc[4 * i + 3]);
            }
        }
    }

    if (n < N) {
        float* pr = part + (size_t)blockIdx.y * 64 * N + n;
#pragma unroll
        for (int i = 0; i < 16; ++i)
            pr[(size_t)(16 * wv + i) * N] = acc[i];
    }
}

__global__ __launch_bounds__(256) void fc_reduce(const float* __restrict__ part,
                                                 const float* __restrict__ bias,
                                                 float* __restrict__ out,
                                                 int S, int N) {
    int n = blockIdx.x * 256 + threadIdx.x;
    int m = blockIdx.y;
    if (n >= N) return;
    float s = bias[n];
    for (int i = 0; i < S; ++i)
        s += part[(size_t)i * 64 * N + (size_t)m * N + n];
    out[(size_t)m * N + n] = s;
}

extern "C" void kernel_launch(void* const* d_in, const int* in_sizes, int n_in,
                              void* d_out, int out_size, void* d_ws, size_t ws_size,
                              hipStream_t stream) {
    const float* x1  = (const float*)d_in[0];
    const float* x2  = (const float*)d_in[1];
    const float* wx1 = (const float*)d_in[2];
    const float* wh1 = (const float*)d_in[3];
    const float* bx1 = (const float*)d_in[4];
    const float* bh1 = (const float*)d_in[5];
    const float* wx2 = (const float*)d_in[6];
    const float* wh2 = (const float*)d_in[7];
    const float* bx2 = (const float*)d_in[8];
    const float* bh2 = (const float*)d_in[9];
    const float* fw2 = (const float*)d_in[10];
    const float* fb2 = (const float*)d_in[11];
    const float* fw3 = (const float*)d_in[12];
    const float* fb3 = (const float*)d_in[13];
    const float* fw4 = (const float*)d_in[14];
    const float* fb4 = (const float*)d_in[15];
    const float* fw5 = (const float*)d_in[16];
    const float* fb5 = (const float*)d_in[17];

    char* ws = (char*)d_ws;
    float* feat = (float*)ws;                                   // [64][7040]
    float* t1   = feat + (size_t)64 * 7040;                     // [64][3400]
    float* t2   = t1   + (size_t)64 * 3400;                     // [64][1000]
    float* t3   = t2   + (size_t)64 * 1000;                     // [64][500]
    float* part = t3   + (size_t)64 * 500;                      // up to 27*64*1000 / 14*64*3400
    float* o    = (float*)d_out;                                // [64][50]

    lstm_kernel<<<dim3(440), dim3(256), 0, stream>>>(
        x1, x2, wx1, wh1, bx1, bh1, wx2, wh2, bx2, bh2, feat);

    fc_gemm<<<dim3(54, 14), dim3(256), 0, stream>>>(feat, fw2, part, 7040, 3400, 512);
    fc_reduce<<<dim3(14, 64), dim3(256), 0, stream>>>(part, fb2, t1, 14, 3400);

    fc_gemm<<<dim3(16, 27), dim3(256), 0, stream>>>(t1, fw3, part, 3400, 1000, 128);
    fc_reduce<<<dim3(4, 64), dim3(256), 0, stream>>>(part, fb3, t2, 27, 1000);

    fc_gemm<<<dim3(8, 8), dim3(256), 0, stream>>>(t2, fw4, part, 1000, 500, 128);
    fc_reduce<<<dim3(2, 64), dim3(256), 0, stream>>>(part, fb4, t3, 8, 500);

    fc_gemm<<<dim3(1, 4), dim3(256), 0, stream>>>(t3, fw5, part, 500, 50, 128);
    fc_reduce<<<dim3(1, 64), dim3(256), 0, stream>>>(part, fb5, o, 4, 50);
}